// Round 1
// 882.063 us; speedup vs baseline: 1.1135x; 1.1135x over previous
//
#include <hip/hip_runtime.h>
#include <stdint.h>

#define BDIM 16384
#define HDIM 1024
#define BHSZ (BDIM * HDIM)

typedef unsigned short u16;
typedef __attribute__((ext_vector_type(8))) short short8;   // 8 bf16 (4 VGPRs) MFMA A/B frag
typedef __attribute__((ext_vector_type(4))) float floatx4;  // MFMA C/D frag

typedef __attribute__((address_space(1))) const void gvoid;
typedef __attribute__((address_space(3))) void lvoid;

__device__ __forceinline__ float bf2f(u16 u) {
  union { uint32_t i; float f; } c; c.i = ((uint32_t)u) << 16; return c.f;
}
__device__ __forceinline__ u16 f2bf(float f) {
  union { float f; uint32_t i; } c; c.f = f;
  uint32_t r = (c.i + 0x7fffu + ((c.i >> 16) & 1u)) >> 16;
  return (u16)r;
}
__device__ __forceinline__ uint4 pack8(const float* f) {
  uint4 v;
  v.x = (uint32_t)f2bf(f[0]) | ((uint32_t)f2bf(f[1]) << 16);
  v.y = (uint32_t)f2bf(f[2]) | ((uint32_t)f2bf(f[3]) << 16);
  v.z = (uint32_t)f2bf(f[4]) | ((uint32_t)f2bf(f[5]) << 16);
  v.w = (uint32_t)f2bf(f[6]) | ((uint32_t)f2bf(f[7]) << 16);
  return v;
}
__device__ __forceinline__ void unpack8(uint4 v, float* f) {
  const uint32_t w[4] = {v.x, v.y, v.z, v.w};
#pragma unroll
  for (int j = 0; j < 4; ++j) {
    f[2 * j]     = bf2f((u16)(w[j] & 0xffffu));
    f[2 * j + 1] = bf2f((u16)(w[j] >> 16));
  }
}
__device__ __forceinline__ void ld8(const float* p, float* f) {
  float4 v0 = *(const float4*)(p);
  float4 v1 = *(const float4*)(p + 4);
  f[0] = v0.x; f[1] = v0.y; f[2] = v0.z; f[3] = v0.w;
  f[4] = v1.x; f[5] = v1.y; f[6] = v1.z; f[7] = v1.w;
}
__device__ __forceinline__ void st8(float* p, const float* f) {
  *(float4*)(p)     = (float4){f[0], f[1], f[2], f[3]};
  *(float4*)(p + 4) = (float4){f[4], f[5], f[6], f[7]};
}

// ---------------------------------------------------------------------------
// fp32 -> bf16 convert (weights)
// ---------------------------------------------------------------------------
__global__ __launch_bounds__(256) void f2b_kernel(
    const float* __restrict__ in, u16* __restrict__ out) {
  const int idx = (blockIdx.x * 256 + threadIdx.x) * 8;
  float f[8];
  ld8(in + idx, f);
  *(uint4*)(out + idx) = pack8(f);
}

// ---------------------------------------------------------------------------
// fused mix: one pass over x/alpha producing xk, xv, xr (bf16) + fp32 x copy
// ---------------------------------------------------------------------------
__global__ __launch_bounds__(256) void mix_all_kernel(
    const float* __restrict__ x, const float* __restrict__ alpha,
    const float* __restrict__ tmk, const float* __restrict__ tmv,
    const float* __restrict__ tmr, u16* __restrict__ xk,
    u16* __restrict__ xv, u16* __restrict__ xr,
    float* __restrict__ xcopy) {
  const int idx = (blockIdx.x * 256 + threadIdx.x) * 8;
  const int h = idx & (HDIM - 1);
  float xf[8], af[8], tk[8], tv[8], tr[8];
  ld8(x + idx, xf);
  ld8(alpha + idx, af);
  ld8(tmk + h, tk);
  ld8(tmv + h, tv);
  ld8(tmr + h, tr);
  float ok[8], ov[8], orr[8];
#pragma unroll
  for (int j = 0; j < 8; ++j) {
    ok[j]  = xf[j] * tk[j] + af[j] * (1.0f - tk[j]);
    ov[j]  = xf[j] * tv[j] + af[j] * (1.0f - tv[j]);
    orr[j] = xf[j] * tr[j] + af[j] * (1.0f - tr[j]);
  }
  *(uint4*)(xk + idx) = pack8(ok);
  *(uint4*)(xv + idx) = pack8(ov);
  *(uint4*)(xr + idx) = pack8(orr);
  st8(xcopy + idx, xf);
}

// ---------------------------------------------------------------------------
// GEMM core: acc[4][4] = A[M,K](bf16) @ W[N,K]^T(bf16) for one 128x128 tile
// (m97 structure: BK=32, global_load_lds width=16, 4 waves 2x2, 4x4 MFMAs)
// ---------------------------------------------------------------------------
__device__ __forceinline__ void gemm_core(
    const u16* __restrict__ A, const u16* __restrict__ W, int K,
    int mBase, int nBase, u16* As, u16* Bs, floatx4 acc[4][4]) {
  const int tid = threadIdx.x;
  const int lane = tid & 63;
  const int wave = tid >> 6;
  const int wm = (wave >> 1) * 64;
  const int wn = (wave & 1) * 64;
  const int lm = lane & 15;
  const int lk = (lane >> 4) * 8;

#pragma unroll
  for (int i = 0; i < 4; ++i)
#pragma unroll
    for (int j = 0; j < 4; ++j) acc[i][j] = (floatx4){0.f, 0.f, 0.f, 0.f};

  for (int k0 = 0; k0 < K; k0 += 32) {
#pragma unroll
    for (int p = 0; p < 2; ++p) {
      const int g = tid + p * 256;               // 0..511
      const int row = g >> 2;                    // 0..127
      const int col = (g & 3) * 8;               // 0/8/16/24
      const u16* ga = A + (size_t)(mBase + row) * K + (k0 + col);
      const u16* gb = W + (size_t)(nBase + row) * K + (k0 + col);
      __builtin_amdgcn_global_load_lds((gvoid*)ga, (lvoid*)(As + g * 8), 16, 0, 0);
      __builtin_amdgcn_global_load_lds((gvoid*)gb, (lvoid*)(Bs + g * 8), 16, 0, 0);
    }
    __syncthreads();

    short8 a[4], b[4];
#pragma unroll
    for (int i = 0; i < 4; ++i)
      a[i] = *(const short8*)(As + (wm + i * 16 + lm) * 32 + lk);
#pragma unroll
    for (int i = 0; i < 4; ++i)
      b[i] = *(const short8*)(Bs + (wn + i * 16 + lm) * 32 + lk);
#pragma unroll
    for (int mi = 0; mi < 4; ++mi)
#pragma unroll
      for (int ni = 0; ni < 4; ++ni)
        acc[mi][ni] = __builtin_amdgcn_mfma_f32_16x16x32_bf16(
            a[mi], b[ni], acc[mi][ni], 0, 0, 0);
    __syncthreads();
  }
}

// C/D layout [m89-verified]: col = lane&15, row = (lane>>4)*4 + reg

// GEMM writing bf16 C (for k, v)
__global__ __launch_bounds__(256) void gemm_bf16out(
    const u16* __restrict__ A, const u16* __restrict__ W,
    u16* __restrict__ C, int K, int N) {
  __shared__ u16 As[128 * 32];
  __shared__ u16 Bs[128 * 32];
  floatx4 acc[4][4];
  const int mBase = blockIdx.y * 128;
  const int nBase = blockIdx.x * 128;
  gemm_core(A, W, K, mBase, nBase, As, Bs, acc);
  const int lane = threadIdx.x & 63;
  const int wave = threadIdx.x >> 6;
  const int wm = (wave >> 1) * 64, wn = (wave & 1) * 64;
  const int lm = lane & 15, rBase = (lane >> 4) * 4;
#pragma unroll
  for (int mi = 0; mi < 4; ++mi)
#pragma unroll
    for (int ni = 0; ni < 4; ++ni) {
      const int gn = nBase + wn + ni * 16 + lm;
#pragma unroll
      for (int r = 0; r < 4; ++r) {
        const int gm = mBase + wm + mi * 16 + rBase + r;
        C[(size_t)gm * N + gn] = f2bf(acc[mi][ni][r]);
      }
    }
}

// GEMM writing bf16 sigmoid(C) (for r)
__global__ __launch_bounds__(256) void gemm_sig_bf16out(
    const u16* __restrict__ A, const u16* __restrict__ W,
    u16* __restrict__ C, int K, int N) {
  __shared__ u16 As[128 * 32];
  __shared__ u16 Bs[128 * 32];
  floatx4 acc[4][4];
  const int mBase = blockIdx.y * 128;
  const int nBase = blockIdx.x * 128;
  gemm_core(A, W, K, mBase, nBase, As, Bs, acc);
  const int lane = threadIdx.x & 63;
  const int wave = threadIdx.x >> 6;
  const int wm = (wave >> 1) * 64, wn = (wave & 1) * 64;
  const int lm = lane & 15, rBase = (lane >> 4) * 4;
#pragma unroll
  for (int mi = 0; mi < 4; ++mi)
#pragma unroll
    for (int ni = 0; ni < 4; ++ni) {
      const int gn = nBase + wn + ni * 16 + lm;
#pragma unroll
      for (int r = 0; r < 4; ++r) {
        const int gm = mBase + wm + mi * 16 + rBase + r;
        const float rr = 1.0f / (1.0f + __expf(-acc[mi][ni][r]));
        C[(size_t)gm * N + gn] = f2bf(rr);
      }
    }
}

// GEMM writing fp32 C (final out = (r*wkv) @ Wo^T)
__global__ __launch_bounds__(256) void gemm_f32out(
    const u16* __restrict__ A, const u16* __restrict__ W,
    float* __restrict__ C, int K, int N) {
  __shared__ u16 As[128 * 32];
  __shared__ u16 Bs[128 * 32];
  floatx4 acc[4][4];
  const int mBase = blockIdx.y * 128;
  const int nBase = blockIdx.x * 128;
  gemm_core(A, W, K, mBase, nBase, As, Bs, acc);
  const int lane = threadIdx.x & 63;
  const int wave = threadIdx.x >> 6;
  const int wm = (wave >> 1) * 64, wn = (wave & 1) * 64;
  const int lm = lane & 15, rBase = (lane >> 4) * 4;
#pragma unroll
  for (int mi = 0; mi < 4; ++mi)
#pragma unroll
    for (int ni = 0; ni < 4; ++ni) {
      const int gn = nBase + wn + ni * 16 + lm;
#pragma unroll
      for (int r = 0; r < 4; ++r) {
        const int gm = mBase + wm + mi * 16 + rBase + r;
        C[(size_t)gm * N + gn] = acc[mi][ni][r];
      }
    }
}

// ---------------------------------------------------------------------------
// WKV elementwise (fully vectorized, 8 elems/thread):
//   reads r,k,v (bf16), aa,bb,pp (fp32), tdec/tfirst (fp32 per-col)
//   writes rwkv (bf16, IN PLACE over k) and naa/nbb/qq2 (fp32)
// ---------------------------------------------------------------------------
__global__ __launch_bounds__(256) void wkv_kernel(
    const u16* __restrict__ rb, u16* __restrict__ kb,
    const u16* __restrict__ vb, const float* __restrict__ aa,
    const float* __restrict__ bb, const float* __restrict__ pp,
    const float* __restrict__ tdec, const float* __restrict__ tfirst,
    float* __restrict__ naa, float* __restrict__ nbb,
    float* __restrict__ qq2) {
  const int idx = (blockIdx.x * 256 + threadIdx.x) * 8;
  const int h = idx & (HDIM - 1);
  float rf[8], kf[8], vf[8], af[8], bfv[8], pf[8], tdf[8], tff[8];
  unpack8(*(const uint4*)(rb + idx), rf);
  unpack8(*(const uint4*)(kb + idx), kf);
  unpack8(*(const uint4*)(vb + idx), vf);
  ld8(aa + idx, af);
  ld8(bb + idx, bfv);
  ld8(pp + idx, pf);
  ld8(tdec + h, tdf);
  ld8(tfirst + h, tff);
  float rw[8], na[8], nb[8], q2[8];
#pragma unroll
  for (int j = 0; j < 8; ++j) {
    const float kk = kf[j], vv = vf[j];
    const float A_ = af[j], B_ = bfv[j], P_ = pf[j];
    const float ww = tff[j] + kk;
    const float qq = fmaxf(P_, ww);
    const float e1 = __expf(P_ - qq);
    const float e2 = __expf(ww - qq);
    const float wkvv = (e1 * A_ + e2 * vv) / (e1 * B_ + e2);
    rw[j] = rf[j] * wkvv;
    const float ww2 = P_ + tdf[j];
    const float q = fmaxf(ww2, kk);
    const float e1b = __expf(ww2 - q);
    const float e2b = __expf(kk - q);
    na[j] = e1b * A_ + e2b * vv;
    nb[j] = e1b * B_ + e2b;
    q2[j] = q;
  }
  *(uint4*)(kb + idx) = pack8(rw);   // rwkv over k (same thread, same addrs)
  st8(naa + idx, na);
  st8(nbb + idx, nb);
  st8(qq2 + idx, q2);
}

// ---------------------------------------------------------------------------
extern "C" void kernel_launch(void* const* d_in, const int* in_sizes, int n_in,
                              void* d_out, int out_size, void* d_ws, size_t ws_size,
                              hipStream_t stream) {
  const float* x      = (const float*)d_in[0];
  const float* alpha  = (const float*)d_in[1];
  const float* aa     = (const float*)d_in[2];
  const float* bb     = (const float*)d_in[3];
  const float* pp     = (const float*)d_in[4];
  const float* tdec   = (const float*)d_in[5];
  const float* tfirst = (const float*)d_in[6];
  const float* tmk    = (const float*)d_in[7];
  const float* tmv    = (const float*)d_in[8];
  const float* tmr    = (const float*)d_in[9];
  const float* Wk     = (const float*)d_in[10];
  const float* Wv     = (const float*)d_in[11];
  const float* Wr     = (const float*)d_in[12];
  const float* Wo     = (const float*)d_in[13];

  float* out  = (float*)d_out;              // output 0: out
  float* outx = out + (size_t)BHSZ;         // output 1: x (verbatim copy)
  float* naa  = out + 2 * (size_t)BHSZ;     // output 2: next_aa
  float* nbb  = out + 3 * (size_t)BHSZ;     // output 3: next_bb
  float* qq2  = out + 4 * (size_t)BHSZ;     // output 4: qq2

  // ws (bf16 scratch, 98 MB): xr | kbuf(->rwkv) | vbuf | wbuf(2 MB, reused 4x)
  u16* xrb = (u16*)d_ws;
  u16* kb  = xrb + (size_t)BHSZ;
  u16* vb  = kb + (size_t)BHSZ;
  u16* wb  = vb + (size_t)BHSZ;

  // output-region scratch (each region dead until its real writer runs):
  //   xk lives in naa region (naa written only by wkv_kernel, after gemm k)
  //   xv lives in qq2 region (qq2 written only by wkv_kernel, after gemm v)
  //   r  lives in out region (out written only by final gemm, after wkv)
  u16* xkb = (u16*)naa;
  u16* xvb = (u16*)qq2;
  u16* rb  = (u16*)out;

  const dim3 gEW(BHSZ / (256 * 8));
  const dim3 gW(HDIM * HDIM / (256 * 8));
  const dim3 gG(HDIM / 128, BDIM / 128);

  // one pass over x/alpha -> xk, xv, xr (bf16) + verbatim x copy
  mix_all_kernel<<<gEW, 256, 0, stream>>>(x, alpha, tmk, tmv, tmr,
                                          xkb, xvb, xrb, outx);
  // k = xk @ Wk^T
  f2b_kernel<<<gW, 256, 0, stream>>>(Wk, wb);
  gemm_bf16out<<<gG, 256, 0, stream>>>(xkb, wb, kb, HDIM, HDIM);
  // v = xv @ Wv^T
  f2b_kernel<<<gW, 256, 0, stream>>>(Wv, wb);
  gemm_bf16out<<<gG, 256, 0, stream>>>(xvb, wb, vb, HDIM, HDIM);
  // r = sigmoid(xr @ Wr^T)  (bf16, into out-region scratch)
  f2b_kernel<<<gW, 256, 0, stream>>>(Wr, wb);
  gemm_sig_bf16out<<<gG, 256, 0, stream>>>(xrb, wb, rb, HDIM, HDIM);
  // WKV elementwise: kb <- r*wkv; naa/nbb/qq2 written (freeing their scratch)
  wkv_kernel<<<gEW, 256, 0, stream>>>(rb, kb, vb, aa, bb, pp, tdec, tfirst,
                                      naa, nbb, qq2);
  // out = (r*wkv) @ Wo^T  (overwrites the dead r scratch)
  f2b_kernel<<<gW, 256, 0, stream>>>(Wo, wb);
  gemm_f32out<<<gG, 256, 0, stream>>>(kb, wb, out, HDIM, HDIM);
}